// Round 6
// baseline (405.066 us; speedup 1.0000x reference)
//
#include <hip/hip_runtime.h>
#include <stdint.h>

typedef unsigned int u32;
typedef unsigned short u16;
typedef unsigned char u8;
typedef unsigned long long u64;
typedef _Float16 h2 __attribute__((ext_vector_type(2)));
typedef _Float16 h4 __attribute__((ext_vector_type(4)));
typedef _Float16 h8 __attribute__((ext_vector_type(8)));
typedef float f4 __attribute__((ext_vector_type(4)));

#define DEV __device__ __forceinline__

constexpr int HWp = 9216;   // 96*96

// ---------- workspace layout (bytes) ----------
constexpr size_t O_I16 = 0;                          // f16 [b][9216][48]: th 0-15, ph 16-31, g 32-47
constexpr size_t N_I16 = 2ull * 9216 * 48;           // halves
constexpr size_t O_Z   = O_I16 + N_I16 * 2;          // f32 [b][576][49][16] per-query z (normalized)
constexpr size_t N_Z   = 2ull * 576 * 784;
constexpr size_t O_FLG = O_Z + N_Z * 4;              // 2 u32: vflag, wflag
constexpr size_t O_WT  = O_FLG + 16;                 // f32 weight stash
constexpr int W_TH = 0, B_TH = 1024, W_PH = 1040, B_PH = 2064, W_G = 2080, B_G = 3104,
              W_W = 3120, B_W = 4144, W_C = 4208, B_C = 12400, N_WT = 12464;
constexpr size_t O_W1  = O_WT + (size_t)N_WT * 4;    // f32 [64][16] = wc33[:, :64] @ ww
constexpr size_t O_B0  = O_W1 + 1024 * 4;            // f32 [64] folded bias
constexpr size_t O_MC  = O_B0 + 256;                 // [96] u8 match counts
constexpr size_t O_MQ  = O_MC + 128;                 // [96][4] u8 query index (per dim)
constexpr size_t O_MR  = O_MQ + 384;                 // [96][4] u8 patch offset (per dim)
constexpr size_t WS_NEED = O_MR + 384;               // ~5.4 MB

DEV float bf2f(u16 x) { return __uint_as_float(((u32)x) << 16); }
DEV int clampi(int v, int lo, int hi) { return v < lo ? lo : (v > hi ? hi : v); }
DEV float loadIn(const void* base, size_t idx, bool isF32) {
  return isF32 ? ((const float*)base)[idx] : bf2f(((const u16*)base)[idx]);
}
DEV float dot2(h2 a, h2 b, float c) {
#if __has_builtin(__builtin_amdgcn_fdot2)
  return __builtin_amdgcn_fdot2(a, b, c, false);
#else
  return c + (float)a[0]*(float)b[0] + (float)a[1]*(float)b[1];
#endif
}
DEV float dot8(h8 a, h8 b, float c) {
  c = dot2(__builtin_shufflevector(a,a,0,1), __builtin_shufflevector(b,b,0,1), c);
  c = dot2(__builtin_shufflevector(a,a,2,3), __builtin_shufflevector(b,b,2,3), c);
  c = dot2(__builtin_shufflevector(a,a,4,5), __builtin_shufflevector(b,b,4,5), c);
  c = dot2(__builtin_shufflevector(a,a,6,7), __builtin_shufflevector(b,b,6,7), c);
  return c;
}

// ---------- KZ (1 block): dtype flags; f32 weight stash; folded W1/B0; match tables ----------
__global__ __launch_bounds__(256) void kz_prep(
    const void* vid,
    const void* wth, const void* bth, const void* wph, const void* bph,
    const void* wg, const void* bg, const void* ww, const void* bw,
    const void* wc33, const void* bc33, u8* ws)
{
  int tid = threadIdx.x;
  __shared__ int red[256];
  {
    const u16* p = (const u16*)vid;
    int h = 0;
    for (int i = tid; i < 8192; i += 256) h += ((((u32)p[i] >> 7) & 0xFFu) >= 0xC8u) ? 1 : 0;
    red[tid] = h;
  }
  __syncthreads();
  if (tid == 0) { int t = 0; for (int i = 0; i < 256; ++i) t += red[i]; red[0] = t; }
  __syncthreads();
  const bool vf = red[0] >= 32;
  __syncthreads();
  {
    const u16* p = (const u16*)wc33;
    int h = 0;
    for (int i = tid; i < 8192; i += 256) h += ((((u32)p[i] >> 7) & 0xFFu) >= 0xC8u) ? 1 : 0;
    red[tid] = h;
  }
  __syncthreads();
  if (tid == 0) { int t = 0; for (int i = 0; i < 256; ++i) t += red[i]; red[0] = t; }
  __syncthreads();
  const bool wf = red[0] >= 32;
  if (tid == 0) { ((u32*)(ws + O_FLG))[0] = vf ? 1u : 0u; ((u32*)(ws + O_FLG))[1] = wf ? 1u : 0u; }

  float* WT = (float*)(ws + O_WT);
  const void* srcs[10] = { wth, bth, wph, bph, wg, bg, ww, bw, wc33, bc33 };
  const int offs[10]   = { W_TH, B_TH, W_PH, B_PH, W_G, B_G, W_W, B_W, W_C, B_C };
  const int lens[10]   = { 1024, 16, 1024, 16, 1024, 16, 1024, 64, 8192, 64 };
  for (int a = 0; a < 10; ++a) {
    const void* s = srcs[a];
    for (int i = tid; i < lens[a]; i += 256)
      WT[offs[a] + i] = wf ? ((const float*)s)[i] : bf2f(((const u16*)s)[i]);
  }
  float* W1 = (float*)(ws + O_W1);
  float* B0 = (float*)(ws + O_B0);
  for (int e = tid; e < 1024; e += 256) {
    int o = e >> 4, ci = e & 15;
    float s = 0.f;
    for (int c = 0; c < 64; ++c) s += loadIn(wc33, o*128 + c, wf) * loadIn(ww, c*16 + ci, wf);
    W1[e] = s;
  }
  if (tid < 64) {
    float s = loadIn(bc33, tid, wf);
    for (int c = 0; c < 64; ++c) s += loadIn(wc33, tid*128 + c, wf) * loadIn(bw, c, wf);
    B0[tid] = s;
  }
  if (tid < 96) {  // matches(v) = {(qi, off): clip(4*qi + off - 3, 0, 95) == v}; cnt == reference scatter count
    u8 *Mc = ws + O_MC, *MQ = ws + O_MQ, *MR = ws + O_MR;
    int cnt = 0;
    for (int qi = 0; qi < 24; ++qi)
      for (int off = 0; off < 7; ++off) {
        int p = clampi(qi*4 + off - 3, 0, 95);
        if (p == tid && cnt < 4) { MQ[tid*4 + cnt] = (u8)qi; MR[tid*4 + cnt] = (u8)off; ++cnt; }
      }
    Mc[tid] = (u8)cnt;
  }
}

// ---------- K1: conv1x1 -> channel-last f16 image [b][px][48] ----------
__global__ __launch_bounds__(256, 2) void k1_conv(const void* vid, u8* ws)
{
  __shared__ float vidL[64 * 65];        // [px][c] pad 65
  __shared__ float wL[48 * 65];          // [o][c] pad 65
  __shared__ float bL[48];
  __shared__ __align__(16) _Float16 outL[64 * 48];
  int tid = threadIdx.x;
  int g0 = blockIdx.x * 64;
  int b = g0 / HWp, px0 = g0 % HWp;
  const float* WT = (const float*)(ws + O_WT);

  for (int e = tid; e < 3072; e += 256) {
    int o = e >> 6, c = e & 63;
    float w = (o < 16) ? WT[W_TH + o*64 + c] : (o < 32) ? WT[W_PH + (o-16)*64 + c] : WT[W_G + (o-32)*64 + c];
    wL[o*65 + c] = w;
  }
  if (tid < 48) bL[tid] = (tid < 16) ? WT[B_TH + tid] : (tid < 32) ? WT[B_PH + tid - 16] : WT[B_G + tid - 32];
  const bool vf = ((const u32*)(ws + O_FLG))[0] != 0;
  if (vf) {
    const float* v = (const float*)vid;
    for (int e = tid; e < 4096; e += 256) { int c = e >> 6, p = e & 63; vidL[p*65 + c] = v[(size_t)(b*64 + c)*HWp + px0 + p]; }
  } else {
    const u16* v = (const u16*)vid;
    for (int e = tid; e < 4096; e += 256) { int c = e >> 6, p = e & 63; vidL[p*65 + c] = bf2f(v[(size_t)(b*64 + c)*HWp + px0 + p]); }
  }
  __syncthreads();

  int px = tid >> 2, h = tid & 3;
  float acc[12];
#pragma unroll
  for (int j = 0; j < 12; ++j) acc[j] = bL[h*12 + j];
  for (int c = 0; c < 64; ++c) {
    float v = vidL[px*65 + c];
#pragma unroll
    for (int j = 0; j < 12; ++j) acc[j] += wL[(h*12 + j)*65 + c] * v;
  }
#pragma unroll
  for (int j = 0; j < 12; ++j) outL[px*48 + h*12 + j] = (_Float16)acc[j];
  __syncthreads();

  _Float16* img = (_Float16*)(ws + O_I16);
  for (int e = tid; e < 384; e += 256) {   // coalesced h8 stores
    int p = e / 6, seg = e % 6;
    *(h8*)(img + (size_t)(b*HWp + px0 + p)*48 + seg*8) = *(const h8*)&outL[p*48 + seg*8];
  }
}

// ---------- K2: LDS-tiled attention; NO atomics — per-query z store ----------
__global__ __launch_bounds__(256, 4) void k2_attn(u8* ws)
{
  __shared__ __align__(16) _Float16 tA[729*8], tB[729*8];  // phi(then g) ch0-7 / ch8-15 planes
  __shared__ __align__(16) _Float16 thA[49*8], thB[49*8];  // theta planes
  __shared__ float scL[441];
  __shared__ u8 crL[441], ccL[441];
  __shared__ u16 selL[100];
  __shared__ u32 wgtH[100];   // normalized weight as packed h2

  const int tid = threadIdx.x, blk = blockIdx.x;
  const int b = blk / 576, q = blk % 576;
  const int qi = (q / 24) * 4, qj = (q % 24) * 4;
  const _Float16* I = (const _Float16*)(ws + O_I16) + (size_t)b * HWp * 48;

  for (int e = tid; e < 441; e += 256) {
    int d1 = e / 21, d2 = e % 21;
    crL[e] = (u8)clampi(qi + d1 - 10, 0, 95);
    ccL[e] = (u8)clampi(qj + d2 - 10, 0, 95);
  }
  for (int e = tid; e < 98; e += 256) {   // theta patch
    int p = e >> 1, hf = e & 1, di = p / 7, dj = p % 7;
    int ty = clampi(qi + di - 3, 0, 95), tx = clampi(qj + dj - 3, 0, 95);
    *(h8*)&(hf ? thB : thA)[p*8] = *(const h8*)(I + (size_t)(ty*96 + tx)*48 + hf*8);
  }
  for (int e = tid; e < 1458; e += 256) { // phi tile: row t holds image row clip(qi-13+t)
    int p = e >> 1, hf = e & 1, row = p / 27, col = p % 27;
    int gy = clampi(qi - 13 + row, 0, 95), gx = clampi(qj - 13 + col, 0, 95);
    *(h8*)&(hf ? tB : tA)[p*8] = *(const h8*)(I + (size_t)(gy*96 + gx)*48 + 16 + hf*8);
  }
  __syncthreads();

  { // scores: direct double-clip rebased into tile
    int c0 = tid;
    int c1 = (tid < 185) ? tid + 256 : tid;
    int cr0 = crL[c0], cc0 = ccL[c0], cr1 = crL[c1], cc1 = ccL[c1];
    int ro0[7], co0[7], ro1[7], co1[7];
#pragma unroll
    for (int i = 0; i < 7; ++i) {
      ro0[i] = (clampi(cr0 + i - 3, 0, 95) - qi + 13) * 216;  // *27*8
      co0[i] = (clampi(cc0 + i - 3, 0, 95) - qj + 13) * 8;
      ro1[i] = (clampi(cr1 + i - 3, 0, 95) - qi + 13) * 216;
      co1[i] = (clampi(cc1 + i - 3, 0, 95) - qj + 13) * 8;
    }
    float a0 = 0.f, a1 = 0.f;
    for (int di = 0; di < 7; ++di) {
#pragma unroll
      for (int dj = 0; dj < 7; ++dj) {
        int pp = di*7 + dj;
        h8 ta = *(const h8*)&thA[pp*8];
        h8 tb = *(const h8*)&thB[pp*8];
        int o0 = ro0[di] + co0[dj], o1 = ro1[di] + co1[dj];
        a0 = dot8(ta, *(const h8*)&tA[o0], a0);
        a0 = dot8(tb, *(const h8*)&tB[o0], a0);
        a1 = dot8(ta, *(const h8*)&tA[o1], a1);
        a1 = dot8(tb, *(const h8*)&tB[o1], a1);
      }
    }
    scL[c0] = a0;
    if (tid < 185) scL[tid + 256] = a1;
  }
  __syncthreads();

  if (tid >= 64) {  // waves 1-3: restage tiles with g while wave 0 selects
    for (int e = tid - 64; e < 1458; e += 192) {
      int p = e >> 1, hf = e & 1, row = p / 27, col = p % 27;
      int gy = clampi(qi - 13 + row, 0, 95), gx = clampi(qj - 13 + col, 0, 95);
      *(h8*)&(hf ? tB : tA)[p*8] = *(const h8*)(I + (size_t)(gy*96 + gx)*48 + 32 + hf*8);
    }
  } else {  // wave 0: exact top-100, stable ties; pack normalized f16 weights
    const int lane = tid;
    u64 kv[7];
#pragma unroll
    for (int s = 0; s < 7; ++s) {
      int idx = s * 64 + lane;
      if (idx < 441) {
        u32 bb = __float_as_uint(scL[idx]);
        u32 ob = (bb & 0x80000000u) ? ~bb : (bb | 0x80000000u);
        kv[s] = ((u64)ob << 32) | (u64)(511 - idx);
      } else kv[s] = 0ull;
    }
    float vmax = 0.f, denom = 0.f, wA = 0.f, wB = 0.f;
    for (int k = 0; k < 100; ++k) {
      u64 m = kv[0];
#pragma unroll
      for (int s = 1; s < 7; ++s) m = (kv[s] > m) ? kv[s] : m;
      for (int off = 1; off < 64; off <<= 1) { u64 o = __shfl_xor(m, off, 64); m = (o > m) ? o : m; }
      int idx = 511 - (int)(m & 0xFFFFFFFFull);
      u32 ob = (u32)(m >> 32);
      u32 bb = (ob & 0x80000000u) ? (ob & 0x7FFFFFFFu) : ~ob;
      float sc = __uint_as_float(bb);
      if (k == 0) vmax = sc;
      float w = __expf(10.f * (sc - vmax));   // identical on all lanes
      denom += w;
      if (lane == 0) selL[k] = (u16)idx;
      if (lane == (k & 63)) { if (k < 64) wA = w; else wB = w; }
      if (lane == (idx & 63)) kv[idx >> 6] = 0ull;
    }
    float inv = 1.f / denom;
    { _Float16 wh = (_Float16)(wA * inv); h2 p2; p2[0] = wh; p2[1] = wh; wgtH[lane] = __builtin_bit_cast(u32, p2); }
    if (lane < 36) { _Float16 wh = (_Float16)(wB * inv); h2 p2; p2[0] = wh; p2[1] = wh; wgtH[lane + 64] = __builtin_bit_cast(u32, p2); }
  }
  __syncthreads();

  // z: thread = (pixel p, channel-quad cq); packed f16 accumulation; coalesced f4 store
  if (tid < 196) {
    int p = tid >> 2, cq = tid & 3;
    int di = p / 7, dj = p % 7;
    const _Float16* base = (cq < 2 ? tA : tB) + (cq & 1) * 4;
    h2 accA; accA[0] = (_Float16)0.f; accA[1] = (_Float16)0.f;
    h2 accB = accA;
    for (int k = 0; k < 100; ++k) {
      int si = selL[k];
      int ty = clampi((int)crL[si] + di - 3, 0, 95) - qi + 13;
      int tx = clampi((int)ccL[si] + dj - 3, 0, 95) - qj + 13;
      h4 g = *(const h4*)&base[(ty*27 + tx)*8];
      h2 w2 = __builtin_bit_cast(h2, wgtH[k]);
      accA += w2 * __builtin_shufflevector(g, g, 0, 1);
      accB += w2 * __builtin_shufflevector(g, g, 2, 3);
    }
    f4 zv; zv[0] = (float)accA[0]; zv[1] = (float)accA[1]; zv[2] = (float)accB[0]; zv[3] = (float)accB[1];
    *(f4*)((float*)(ws + O_Z) + (size_t)(b*576 + q)*784 + tid*4) = zv;   // p*16 + cq*4 == tid*4
  }
}

// ---------- K3: gather overlap-add (match tables) + folded epilogue out = B0 + W1·zn + Wv·vid ----------
__global__ __launch_bounds__(256, 2) void k3_out(const void* vid, float* out, const u8* ws)
{
  __shared__ float znL[16 * 96];
  __shared__ float vidL[64 * 96];
  __shared__ float WvL[32 * 65];
  __shared__ float W1L[32 * 17];
  __shared__ float B0L[32];
  __shared__ u8 McL[96], MQL[384], MRL[384];
  const int tid = threadIdx.x, blk = blockIdx.x;
  const int b = blk / 192, rem = blk % 192, y = rem >> 1, oh = (rem & 1) * 32;
  const float* WT = (const float*)(ws + O_WT);
  const bool vf = ((const u32*)(ws + O_FLG))[0] != 0;

  if (tid < 96) {
    McL[tid] = ws[O_MC + tid];
#pragma unroll
    for (int j = 0; j < 4; ++j) { MQL[tid*4 + j] = ws[O_MQ + tid*4 + j]; MRL[tid*4 + j] = ws[O_MR + tid*4 + j]; }
  }
  if (vf) {
    const float* v = (const float*)vid;
    for (int e = tid; e < 6144; e += 256) { int c = e / 96, x = e % 96; vidL[c*96 + x] = v[(size_t)(b*64 + c)*HWp + y*96 + x]; }
  } else {
    const u16* v = (const u16*)vid;
    for (int e = tid; e < 6144; e += 256) { int c = e / 96, x = e % 96; vidL[c*96 + x] = bf2f(v[(size_t)(b*64 + c)*HWp + y*96 + x]); }
  }
  for (int e = tid; e < 2048; e += 256) { int o = e >> 6, c = e & 63; WvL[o*65 + c] = WT[W_C + (oh + o)*128 + 64 + c]; }
  for (int e = tid; e < 512; e += 256)  { int o = e >> 4, ci = e & 15; W1L[o*17 + ci] = ((const float*)(ws + O_W1))[(oh + o)*16 + ci]; }
  if (tid < 32) B0L[tid] = ((const float*)(ws + O_B0))[oh + tid];
  __syncthreads();

  { // gather zn for this row: ≤ mcy*mcx ≤ 16 f4 loads per (x, channel-quad)
    const float* zG = (const float*)(ws + O_Z) + (size_t)b * 576 * 784;
    const int mcy = McL[y];
    for (int e = tid; e < 384; e += 256) {
      int x = e >> 2, cq = e & 3;
      int mcx = McL[x];
      f4 s = 0.f;
      for (int a = 0; a < mcy; ++a) {
        int qy = MQL[y*4 + a], rr = MRL[y*4 + a];
        size_t rowbase = ((size_t)qy * 24) * 784 + (size_t)(rr * 7) * 16 + cq * 4;
        for (int b2 = 0; b2 < mcx; ++b2) {
          int qx = MQL[x*4 + b2], ss = MRL[x*4 + b2];
          s += *(const f4*)(zG + rowbase + (size_t)qx * 784 + ss * 16);
        }
      }
      float invc = 1.f / (float)(mcy * mcx);
#pragma unroll
      for (int j = 0; j < 4; ++j) znL[(cq*4 + j)*96 + x] = s[j] * invc;
    }
  }
  __syncthreads();

  const int o = tid >> 3, xq = tid & 7;   // 32 o x 8 xq; 12 x per thread
  f4 a0, a1, a2;
  { float bz = B0L[o]; a0 = bz; a1 = bz; a2 = bz; }
  for (int ci = 0; ci < 16; ++ci) {
    float w = W1L[o*17 + ci];
    const f4* zp = (const f4*)&znL[ci*96 + xq*12];
    a0 += zp[0] * w; a1 += zp[1] * w; a2 += zp[2] * w;
  }
  for (int c = 0; c < 64; ++c) {
    float w = WvL[o*65 + c];
    const f4* vp = (const f4*)&vidL[c*96 + xq*12];
    a0 += vp[0] * w; a1 += vp[1] * w; a2 += vp[2] * w;
  }
  float* op = out + (size_t)(b*64 + oh + o) * HWp + y*96 + xq*12;
  *(f4*)(op + 0) = a0; *(f4*)(op + 4) = a1; *(f4*)(op + 8) = a2;
}

extern "C" void kernel_launch(void* const* d_in, const int* in_sizes, int n_in,
                              void* d_out, int out_size, void* d_ws, size_t ws_size,
                              hipStream_t stream)
{
  (void)in_sizes; (void)n_in; (void)out_size;
  const void* vid  = d_in[0];
  const void* wth  = d_in[1];
  const void* bth  = d_in[2];
  const void* wph  = d_in[3];
  const void* bph  = d_in[4];
  const void* wg   = d_in[5];
  const void* bg   = d_in[6];
  const void* ww   = d_in[7];
  const void* bw   = d_in[8];
  const void* wc33 = d_in[9];
  const void* bc33 = d_in[10];
  u8* ws = (u8*)d_ws;
  if (ws_size < WS_NEED) return;

  hipLaunchKernelGGL(kz_prep, dim3(1), dim3(256), 0, stream,
                     vid, wth, bth, wph, bph, wg, bg, ww, bw, wc33, bc33, ws);
  hipLaunchKernelGGL(k1_conv, dim3(288), dim3(256), 0, stream, vid, ws);
  hipLaunchKernelGGL(k2_attn, dim3(1152), dim3(256), 0, stream, ws);
  hipLaunchKernelGGL(k3_out, dim3(384), dim3(256), 0, stream, vid, (float*)d_out, ws);
}

// Round 7
// 245.752 us; speedup vs baseline: 1.6483x; 1.6483x over previous
//
#include <hip/hip_runtime.h>
#include <stdint.h>

typedef unsigned int u32;
typedef unsigned short u16;
typedef unsigned char u8;
typedef unsigned long long u64;
typedef _Float16 h2 __attribute__((ext_vector_type(2)));
typedef _Float16 h4 __attribute__((ext_vector_type(4)));
typedef _Float16 h8 __attribute__((ext_vector_type(8)));
typedef float f4 __attribute__((ext_vector_type(4)));

#define DEV __device__ __forceinline__

constexpr int HWp = 9216;   // 96*96

// ---------- workspace layout (bytes) ----------
constexpr size_t O_I16 = 0;                          // f16 [b][9216][48]: th 0-15, ph 16-31, g 32-47
constexpr size_t N_I16 = 2ull * 9216 * 48;           // halves
constexpr size_t O_Z   = O_I16 + N_I16 * 2;          // f32 [b][576][49][16] per-query z (normalized)
constexpr size_t N_Z   = 2ull * 576 * 784;
constexpr size_t O_FLG = O_Z + N_Z * 4;              // 2 u32: vflag, wflag
constexpr size_t O_WT  = O_FLG + 16;                 // f32 weight stash
constexpr int W_TH = 0, B_TH = 1024, W_PH = 1040, B_PH = 2064, W_G = 2080, B_G = 3104,
              W_W = 3120, B_W = 4144, W_C = 4208, B_C = 12400, N_WT = 12464;
constexpr size_t O_W1  = O_WT + (size_t)N_WT * 4;    // f32 [64][16] = wc33[:, :64] @ ww
constexpr size_t O_B0  = O_W1 + 1024 * 4;            // f32 [64] folded bias
constexpr size_t O_MC  = O_B0 + 256;                 // [96] u8 match counts
constexpr size_t O_MQ  = O_MC + 128;                 // [96][4] u8 query index (per dim)
constexpr size_t O_MR  = O_MQ + 384;                 // [96][4] u8 patch offset (per dim)
constexpr size_t WS_NEED = O_MR + 384;               // ~5.4 MB

DEV float bf2f(u16 x) { return __uint_as_float(((u32)x) << 16); }
DEV int clampi(int v, int lo, int hi) { return v < lo ? lo : (v > hi ? hi : v); }
DEV float loadIn(const void* base, size_t idx, bool isF32) {
  return isF32 ? ((const float*)base)[idx] : bf2f(((const u16*)base)[idx]);
}
DEV float dot2(h2 a, h2 b, float c) {
#if __has_builtin(__builtin_amdgcn_fdot2)
  return __builtin_amdgcn_fdot2(a, b, c, false);
#else
  return c + (float)a[0]*(float)b[0] + (float)a[1]*(float)b[1];
#endif
}
DEV float dot8(h8 a, h8 b, float c) {
  c = dot2(__builtin_shufflevector(a,a,0,1), __builtin_shufflevector(b,b,0,1), c);
  c = dot2(__builtin_shufflevector(a,a,2,3), __builtin_shufflevector(b,b,2,3), c);
  c = dot2(__builtin_shufflevector(a,a,4,5), __builtin_shufflevector(b,b,4,5), c);
  c = dot2(__builtin_shufflevector(a,a,6,7), __builtin_shufflevector(b,b,6,7), c);
  return c;
}

// ---------- KZ (1 block): dtype flags; f32 weight stash; folded W1/B0; match tables ----------
__global__ __launch_bounds__(256) void kz_prep(
    const void* vid,
    const void* wth, const void* bth, const void* wph, const void* bph,
    const void* wg, const void* bg, const void* ww, const void* bw,
    const void* wc33, const void* bc33, u8* ws)
{
  int tid = threadIdx.x;
  __shared__ int red[256];
  {
    const u16* p = (const u16*)vid;
    int h = 0;
    for (int i = tid; i < 8192; i += 256) h += ((((u32)p[i] >> 7) & 0xFFu) >= 0xC8u) ? 1 : 0;
    red[tid] = h;
  }
  __syncthreads();
  if (tid == 0) { int t = 0; for (int i = 0; i < 256; ++i) t += red[i]; red[0] = t; }
  __syncthreads();
  const bool vf = red[0] >= 32;
  __syncthreads();
  {
    const u16* p = (const u16*)wc33;
    int h = 0;
    for (int i = tid; i < 8192; i += 256) h += ((((u32)p[i] >> 7) & 0xFFu) >= 0xC8u) ? 1 : 0;
    red[tid] = h;
  }
  __syncthreads();
  if (tid == 0) { int t = 0; for (int i = 0; i < 256; ++i) t += red[i]; red[0] = t; }
  __syncthreads();
  const bool wf = red[0] >= 32;
  if (tid == 0) { ((u32*)(ws + O_FLG))[0] = vf ? 1u : 0u; ((u32*)(ws + O_FLG))[1] = wf ? 1u : 0u; }

  float* WT = (float*)(ws + O_WT);
  const void* srcs[10] = { wth, bth, wph, bph, wg, bg, ww, bw, wc33, bc33 };
  const int offs[10]   = { W_TH, B_TH, W_PH, B_PH, W_G, B_G, W_W, B_W, W_C, B_C };
  const int lens[10]   = { 1024, 16, 1024, 16, 1024, 16, 1024, 64, 8192, 64 };
  for (int a = 0; a < 10; ++a) {
    const void* s = srcs[a];
    for (int i = tid; i < lens[a]; i += 256)
      WT[offs[a] + i] = wf ? ((const float*)s)[i] : bf2f(((const u16*)s)[i]);
  }
  float* W1 = (float*)(ws + O_W1);
  float* B0 = (float*)(ws + O_B0);
  for (int e = tid; e < 1024; e += 256) {
    int o = e >> 4, ci = e & 15;
    float s = 0.f;
    for (int c = 0; c < 64; ++c) s += loadIn(wc33, o*128 + c, wf) * loadIn(ww, c*16 + ci, wf);
    W1[e] = s;
  }
  if (tid < 64) {
    float s = loadIn(bc33, tid, wf);
    for (int c = 0; c < 64; ++c) s += loadIn(wc33, tid*128 + c, wf) * loadIn(bw, c, wf);
    B0[tid] = s;
  }
  if (tid < 96) {  // matches(v) = {(qi, off): clip(4*qi + off - 3, 0, 95) == v}; cnt == reference scatter count
    u8 *Mc = ws + O_MC, *MQ = ws + O_MQ, *MR = ws + O_MR;
    int cnt = 0;
    for (int qi = 0; qi < 24; ++qi)
      for (int off = 0; off < 7; ++off) {
        int p = clampi(qi*4 + off - 3, 0, 95);
        if (p == tid && cnt < 4) { MQ[tid*4 + cnt] = (u8)qi; MR[tid*4 + cnt] = (u8)off; ++cnt; }
      }
    Mc[tid] = (u8)cnt;
  }
}

// ---------- K1: conv1x1 -> channel-last f16 image [b][px][48] ----------
__global__ __launch_bounds__(256, 2) void k1_conv(const void* vid, u8* ws)
{
  __shared__ float vidL[64 * 65];        // [px][c] pad 65
  __shared__ float wL[48 * 65];          // [o][c] pad 65
  __shared__ float bL[48];
  __shared__ __align__(16) _Float16 outL[64 * 48];
  int tid = threadIdx.x;
  int g0 = blockIdx.x * 64;
  int b = g0 / HWp, px0 = g0 % HWp;
  const float* WT = (const float*)(ws + O_WT);

  for (int e = tid; e < 3072; e += 256) {
    int o = e >> 6, c = e & 63;
    float w = (o < 16) ? WT[W_TH + o*64 + c] : (o < 32) ? WT[W_PH + (o-16)*64 + c] : WT[W_G + (o-32)*64 + c];
    wL[o*65 + c] = w;
  }
  if (tid < 48) bL[tid] = (tid < 16) ? WT[B_TH + tid] : (tid < 32) ? WT[B_PH + tid - 16] : WT[B_G + tid - 32];
  const bool vf = ((const u32*)(ws + O_FLG))[0] != 0;
  if (vf) {
    const float* v = (const float*)vid;
    for (int e = tid; e < 4096; e += 256) { int c = e >> 6, p = e & 63; vidL[p*65 + c] = v[(size_t)(b*64 + c)*HWp + px0 + p]; }
  } else {
    const u16* v = (const u16*)vid;
    for (int e = tid; e < 4096; e += 256) { int c = e >> 6, p = e & 63; vidL[p*65 + c] = bf2f(v[(size_t)(b*64 + c)*HWp + px0 + p]); }
  }
  __syncthreads();

  int px = tid >> 2, h = tid & 3;
  float acc[12];
#pragma unroll
  for (int j = 0; j < 12; ++j) acc[j] = bL[h*12 + j];
  for (int c = 0; c < 64; ++c) {
    float v = vidL[px*65 + c];
#pragma unroll
    for (int j = 0; j < 12; ++j) acc[j] += wL[(h*12 + j)*65 + c] * v;
  }
#pragma unroll
  for (int j = 0; j < 12; ++j) outL[px*48 + h*12 + j] = (_Float16)acc[j];
  __syncthreads();

  _Float16* img = (_Float16*)(ws + O_I16);
  for (int e = tid; e < 384; e += 256) {   // coalesced h8 stores
    int p = e / 6, seg = e % 6;
    *(h8*)(img + (size_t)(b*HWp + px0 + p)*48 + seg*8) = *(const h8*)&outL[p*48 + seg*8];
  }
}

// ---------- K2: LDS-tiled attention; no atomics; NO forced occupancy (spill-free) ----------
__global__ __launch_bounds__(256, 2) void k2_attn(u8* ws)
{
  __shared__ __align__(16) _Float16 tA[729*8], tB[729*8];  // phi(then g) ch0-7 / ch8-15 planes
  __shared__ __align__(16) _Float16 thA[49*8], thB[49*8];  // theta planes
  __shared__ float scL[441];
  __shared__ u8 crL[441], ccL[441];
  __shared__ u16 selL[100];
  __shared__ u32 wgtH[100];   // normalized weight as packed h2

  const int tid = threadIdx.x, blk = blockIdx.x;
  const int b = blk / 576, q = blk % 576;
  const int qi = (q / 24) * 4, qj = (q % 24) * 4;
  const _Float16* I = (const _Float16*)(ws + O_I16) + (size_t)b * HWp * 48;

  for (int e = tid; e < 441; e += 256) {
    int d1 = e / 21, d2 = e % 21;
    crL[e] = (u8)clampi(qi + d1 - 10, 0, 95);
    ccL[e] = (u8)clampi(qj + d2 - 10, 0, 95);
  }
  for (int e = tid; e < 98; e += 256) {   // theta patch
    int p = e >> 1, hf = e & 1, di = p / 7, dj = p % 7;
    int ty = clampi(qi + di - 3, 0, 95), tx = clampi(qj + dj - 3, 0, 95);
    *(h8*)&(hf ? thB : thA)[p*8] = *(const h8*)(I + (size_t)(ty*96 + tx)*48 + hf*8);
  }
  for (int e = tid; e < 1458; e += 256) { // phi tile: row t holds image row clip(qi-13+t)
    int p = e >> 1, hf = e & 1, row = p / 27, col = p % 27;
    int gy = clampi(qi - 13 + row, 0, 95), gx = clampi(qj - 13 + col, 0, 95);
    *(h8*)&(hf ? tB : tA)[p*8] = *(const h8*)(I + (size_t)(gy*96 + gx)*48 + 16 + hf*8);
  }
  __syncthreads();

  { // scores: direct double-clip rebased into tile
    int c0 = tid;
    int c1 = (tid < 185) ? tid + 256 : tid;
    int cr0 = crL[c0], cc0 = ccL[c0], cr1 = crL[c1], cc1 = ccL[c1];
    int ro0[7], co0[7], ro1[7], co1[7];
#pragma unroll
    for (int i = 0; i < 7; ++i) {
      ro0[i] = (clampi(cr0 + i - 3, 0, 95) - qi + 13) * 216;  // *27*8
      co0[i] = (clampi(cc0 + i - 3, 0, 95) - qj + 13) * 8;
      ro1[i] = (clampi(cr1 + i - 3, 0, 95) - qi + 13) * 216;
      co1[i] = (clampi(cc1 + i - 3, 0, 95) - qj + 13) * 8;
    }
    float a0 = 0.f, a1 = 0.f;
    for (int di = 0; di < 7; ++di) {
#pragma unroll
      for (int dj = 0; dj < 7; ++dj) {
        int pp = di*7 + dj;
        h8 ta = *(const h8*)&thA[pp*8];
        h8 tb = *(const h8*)&thB[pp*8];
        int o0 = ro0[di] + co0[dj], o1 = ro1[di] + co1[dj];
        a0 = dot8(ta, *(const h8*)&tA[o0], a0);
        a0 = dot8(tb, *(const h8*)&tB[o0], a0);
        a1 = dot8(ta, *(const h8*)&tA[o1], a1);
        a1 = dot8(tb, *(const h8*)&tB[o1], a1);
      }
    }
    scL[c0] = a0;
    if (tid < 185) scL[tid + 256] = a1;
  }
  __syncthreads();

  if (tid >= 64) {  // waves 1-3: restage tiles with g while wave 0 selects
    for (int e = tid - 64; e < 1458; e += 192) {
      int p = e >> 1, hf = e & 1, row = p / 27, col = p % 27;
      int gy = clampi(qi - 13 + row, 0, 95), gx = clampi(qj - 13 + col, 0, 95);
      *(h8*)&(hf ? tB : tA)[p*8] = *(const h8*)(I + (size_t)(gy*96 + gx)*48 + 32 + hf*8);
    }
  } else {  // wave 0: exact top-100, stable ties; pack normalized f16 weights
    const int lane = tid;
    u64 kv[7];
#pragma unroll
    for (int s = 0; s < 7; ++s) {
      int idx = s * 64 + lane;
      if (idx < 441) {
        u32 bb = __float_as_uint(scL[idx]);
        u32 ob = (bb & 0x80000000u) ? ~bb : (bb | 0x80000000u);
        kv[s] = ((u64)ob << 32) | (u64)(511 - idx);
      } else kv[s] = 0ull;
    }
    float vmax = 0.f, denom = 0.f, wA = 0.f, wB = 0.f;
    for (int k = 0; k < 100; ++k) {
      u64 m = kv[0];
#pragma unroll
      for (int s = 1; s < 7; ++s) m = (kv[s] > m) ? kv[s] : m;
      for (int off = 1; off < 64; off <<= 1) { u64 o = __shfl_xor(m, off, 64); m = (o > m) ? o : m; }
      int idx = 511 - (int)(m & 0xFFFFFFFFull);
      u32 ob = (u32)(m >> 32);
      u32 bb = (ob & 0x80000000u) ? (ob & 0x7FFFFFFFu) : ~ob;
      float sc = __uint_as_float(bb);
      if (k == 0) vmax = sc;
      float w = __expf(10.f * (sc - vmax));   // identical on all lanes
      denom += w;
      if (lane == 0) selL[k] = (u16)idx;
      if (lane == (k & 63)) { if (k < 64) wA = w; else wB = w; }
      if (lane == (idx & 63)) kv[idx >> 6] = 0ull;
    }
    float inv = 1.f / denom;
    { _Float16 wh = (_Float16)(wA * inv); h2 p2; p2[0] = wh; p2[1] = wh; wgtH[lane] = __builtin_bit_cast(u32, p2); }
    if (lane < 36) { _Float16 wh = (_Float16)(wB * inv); h2 p2; p2[0] = wh; p2[1] = wh; wgtH[lane + 64] = __builtin_bit_cast(u32, p2); }
  }
  __syncthreads();

  // z: thread = (pixel p, channel-quad cq); packed f16 accumulation; coalesced f4 store
  if (tid < 196) {
    int p = tid >> 2, cq = tid & 3;
    int di = p / 7, dj = p % 7;
    const _Float16* base = (cq < 2 ? tA : tB) + (cq & 1) * 4;
    h2 accA; accA[0] = (_Float16)0.f; accA[1] = (_Float16)0.f;
    h2 accB = accA;
    for (int k = 0; k < 100; ++k) {
      int si = selL[k];
      int ty = clampi((int)crL[si] + di - 3, 0, 95) - qi + 13;
      int tx = clampi((int)ccL[si] + dj - 3, 0, 95) - qj + 13;
      h4 g = *(const h4*)&base[(ty*27 + tx)*8];
      h2 w2 = __builtin_bit_cast(h2, wgtH[k]);
      accA += w2 * __builtin_shufflevector(g, g, 0, 1);
      accB += w2 * __builtin_shufflevector(g, g, 2, 3);
    }
    f4 zv; zv[0] = (float)accA[0]; zv[1] = (float)accA[1]; zv[2] = (float)accB[0]; zv[3] = (float)accB[1];
    *(f4*)((float*)(ws + O_Z) + (size_t)(b*576 + q)*784 + tid*4) = zv;   // p*16 + cq*4 == tid*4
  }
}

// ---------- K3: gather overlap-add (match tables) + folded epilogue out = B0 + W1·zn + Wv·vid ----------
__global__ __launch_bounds__(256, 2) void k3_out(const void* vid, float* out, const u8* ws)
{
  __shared__ float znL[16 * 96];
  __shared__ float vidL[64 * 96];
  __shared__ float WvL[32 * 65];
  __shared__ float W1L[32 * 17];
  __shared__ float B0L[32];
  __shared__ u8 McL[96], MQL[384], MRL[384];
  const int tid = threadIdx.x, blk = blockIdx.x;
  const int b = blk / 192, rem = blk % 192, y = rem >> 1, oh = (rem & 1) * 32;
  const float* WT = (const float*)(ws + O_WT);
  const bool vf = ((const u32*)(ws + O_FLG))[0] != 0;

  if (tid < 96) {
    McL[tid] = ws[O_MC + tid];
#pragma unroll
    for (int j = 0; j < 4; ++j) { MQL[tid*4 + j] = ws[O_MQ + tid*4 + j]; MRL[tid*4 + j] = ws[O_MR + tid*4 + j]; }
  }
  if (vf) {
    const float* v = (const float*)vid;
    for (int e = tid; e < 6144; e += 256) { int c = e / 96, x = e % 96; vidL[c*96 + x] = v[(size_t)(b*64 + c)*HWp + y*96 + x]; }
  } else {
    const u16* v = (const u16*)vid;
    for (int e = tid; e < 6144; e += 256) { int c = e / 96, x = e % 96; vidL[c*96 + x] = bf2f(v[(size_t)(b*64 + c)*HWp + y*96 + x]); }
  }
  for (int e = tid; e < 2048; e += 256) { int o = e >> 6, c = e & 63; WvL[o*65 + c] = WT[W_C + (oh + o)*128 + 64 + c]; }
  for (int e = tid; e < 512; e += 256)  { int o = e >> 4, ci = e & 15; W1L[o*17 + ci] = ((const float*)(ws + O_W1))[(oh + o)*16 + ci]; }
  if (tid < 32) B0L[tid] = ((const float*)(ws + O_B0))[oh + tid];
  __syncthreads();

  { // gather zn for this row: ≤ mcy*mcx ≤ 16 f4 loads per (x, channel-quad)
    const float* zG = (const float*)(ws + O_Z) + (size_t)b * 576 * 784;
    const int mcy = McL[y];
    for (int e = tid; e < 384; e += 256) {
      int x = e >> 2, cq = e & 3;
      int mcx = McL[x];
      f4 s = 0.f;
      for (int a = 0; a < mcy; ++a) {
        int qy = MQL[y*4 + a], rr = MRL[y*4 + a];
        size_t rowbase = ((size_t)qy * 24) * 784 + (size_t)(rr * 7) * 16 + cq * 4;
        for (int b2 = 0; b2 < mcx; ++b2) {
          int qx = MQL[x*4 + b2], ss = MRL[x*4 + b2];
          s += *(const f4*)(zG + rowbase + (size_t)qx * 784 + ss * 16);
        }
      }
      float invc = 1.f / (float)(mcy * mcx);
#pragma unroll
      for (int j = 0; j < 4; ++j) znL[(cq*4 + j)*96 + x] = s[j] * invc;
    }
  }
  __syncthreads();

  const int o = tid >> 3, xq = tid & 7;   // 32 o x 8 xq; 12 x per thread
  f4 a0, a1, a2;
  { float bz = B0L[o]; a0 = bz; a1 = bz; a2 = bz; }
  for (int ci = 0; ci < 16; ++ci) {
    float w = W1L[o*17 + ci];
    const f4* zp = (const f4*)&znL[ci*96 + xq*12];
    a0 += zp[0] * w; a1 += zp[1] * w; a2 += zp[2] * w;
  }
  for (int c = 0; c < 64; ++c) {
    float w = WvL[o*65 + c];
    const f4* vp = (const f4*)&vidL[c*96 + xq*12];
    a0 += vp[0] * w; a1 += vp[1] * w; a2 += vp[2] * w;
  }
  float* op = out + (size_t)(b*64 + oh + o) * HWp + y*96 + xq*12;
  *(f4*)(op + 0) = a0; *(f4*)(op + 4) = a1; *(f4*)(op + 8) = a2;
}

extern "C" void kernel_launch(void* const* d_in, const int* in_sizes, int n_in,
                              void* d_out, int out_size, void* d_ws, size_t ws_size,
                              hipStream_t stream)
{
  (void)in_sizes; (void)n_in; (void)out_size;
  const void* vid  = d_in[0];
  const void* wth  = d_in[1];
  const void* bth  = d_in[2];
  const void* wph  = d_in[3];
  const void* bph  = d_in[4];
  const void* wg   = d_in[5];
  const void* bg   = d_in[6];
  const void* ww   = d_in[7];
  const void* bw   = d_in[8];
  const void* wc33 = d_in[9];
  const void* bc33 = d_in[10];
  u8* ws = (u8*)d_ws;
  if (ws_size < WS_NEED) return;

  hipLaunchKernelGGL(kz_prep, dim3(1), dim3(256), 0, stream,
                     vid, wth, bth, wph, bph, wg, bg, ww, bw, wc33, bc33, ws);
  hipLaunchKernelGGL(k1_conv, dim3(288), dim3(256), 0, stream, vid, ws);
  hipLaunchKernelGGL(k2_attn, dim3(1152), dim3(256), 0, stream, ws);
  hipLaunchKernelGGL(k3_out, dim3(384), dim3(256), 0, stream, vid, (float*)d_out, ws);
}